// Round 12
// baseline (9254.488 us; speedup 1.0000x reference)
//
#include <hip/hip_runtime.h>
#include <hip/hip_bf16.h>
#include <math.h>

#define B_ 64
#define T_ 1024
#define D_ 512
#define H_ 512
#define M_ 256
#define CC 63
#define SS 64
#define INV_SQRT_2PI 0.3989422804014327f

typedef __attribute__((ext_vector_type(8))) short short8v;
typedef __attribute__((ext_vector_type(4))) float f32x4;

static __device__ __forceinline__ float bf2f(unsigned short u) {
    unsigned int x = ((unsigned int)u) << 16;
    return __uint_as_float(x);
}
static __device__ __forceinline__ unsigned short f2bf(float f) {
    unsigned int x = __float_as_uint(f);
    unsigned int r = (x + 0x7fff + ((x >> 16) & 1)) >> 16;
    return (unsigned short)r;
}
static __device__ __forceinline__ float sigm(float x) {
    return 1.f / (1.f + __expf(-x));
}
static __device__ __forceinline__ float wsum64(float v) {
    for (int o = 32; o > 0; o >>= 1) v += __shfl_xor(v, o, 64);
    return v;
}

// ---------------- prologue ----------------

__global__ __launch_bounds__(256) void k_conv(const float* __restrict__ src,
        unsigned short* __restrict__ dst, int n4) {
    int stride = gridDim.x * 256;
    for (int i = blockIdx.x * 256 + threadIdx.x; i < n4; i += stride) {
        float4 v = ((const float4*)src)[i];
        ushort4 o;
        o.x = f2bf(v.x); o.y = f2bf(v.y); o.z = f2bf(v.z); o.w = f2bf(v.w);
        ((ushort4*)dst)[i] = o;
    }
}

// MFMA bf16 GEMM (r2-proven): clT[b*256+m][t] = bf16(relu(Lbf x psibf^T + psib))
__global__ __launch_bounds__(256) void k_gemm_mfma(
        const unsigned short* __restrict__ Abf,
        const unsigned short* __restrict__ Bbf,
        const float* __restrict__ psib,
        unsigned short* __restrict__ clT) {
    __shared__ unsigned short As[64 * 40];
    __shared__ unsigned short Bs[64 * 40];
    __shared__ unsigned short Os[64 * 72];
    int tid = threadIdx.x;
    int p0 = (blockIdx.x >> 2) * 64;
    int m0 = (blockIdx.x & 3) * 64;
    int w = tid >> 6, l = tid & 63;
    int wp = (w & 1) * 32, wm = (w >> 1) * 32;
    f32x4 acc[2][2] = {};
    int srow = tid >> 2, sc = (tid & 3) * 8;
    for (int k0 = 0; k0 < 512; k0 += 32) {
        __syncthreads();
        *(short8v*)&As[srow * 40 + sc] = *(const short8v*)&Abf[(size_t)(p0 + srow) * 512 + k0 + sc];
        *(short8v*)&Bs[srow * 40 + sc] = *(const short8v*)&Bbf[(size_t)(m0 + srow) * 512 + k0 + sc];
        __syncthreads();
        int koff = (l >> 4) * 8;
        int rlo = l & 15;
        short8v a0 = *(short8v*)&As[(wp + rlo) * 40 + koff];
        short8v a1 = *(short8v*)&As[(wp + 16 + rlo) * 40 + koff];
        short8v b0 = *(short8v*)&Bs[(wm + rlo) * 40 + koff];
        short8v b1 = *(short8v*)&Bs[(wm + 16 + rlo) * 40 + koff];
        acc[0][0] = __builtin_amdgcn_mfma_f32_16x16x32_bf16(a0, b0, acc[0][0], 0, 0, 0);
        acc[0][1] = __builtin_amdgcn_mfma_f32_16x16x32_bf16(a0, b1, acc[0][1], 0, 0, 0);
        acc[1][0] = __builtin_amdgcn_mfma_f32_16x16x32_bf16(a1, b0, acc[1][0], 0, 0, 0);
        acc[1][1] = __builtin_amdgcn_mfma_f32_16x16x32_bf16(a1, b1, acc[1][1], 0, 0, 0);
    }
    __syncthreads();
#pragma unroll
    for (int pi = 0; pi < 2; ++pi)
#pragma unroll
        for (int mi = 0; mi < 2; ++mi)
#pragma unroll
            for (int r = 0; r < 4; ++r) {
                int tl = wp + pi * 16 + (l >> 4) * 4 + r;
                int ml = wm + mi * 16 + (l & 15);
                float v = fmaxf(acc[pi][mi][r] + psib[m0 + ml], 0.f);
                Os[ml * 72 + tl] = f2bf(v);
            }
    __syncthreads();
    int b = p0 >> 10, t0 = p0 & 1023;
    int mm = tid >> 2, c16 = (tid & 3) * 16;
    short8v v0 = *(short8v*)&Os[mm * 72 + c16];
    short8v v1 = *(short8v*)&Os[mm * 72 + c16 + 8];
    size_t base = ((size_t)(b * 256 + m0 + mm)) * 1024 + t0 + c16;
    *(short8v*)&clT[base] = v0;
    *(short8v*)&clT[base + 8] = v1;
}

__global__ __launch_bounds__(256) void k_init(const float* __restrict__ Lf,
        const float* __restrict__ gt,
        float* gtT, float* h0a, float* h1a, float* c0, float* c1,
        float* ctxT0, float* ctxb0) {
    int tid = threadIdx.x, blk = blockIdx.x;
    if (blk < 64) {
        for (int r = tid; r < CC * 64; r += 256) {
            int k = r >> 6, b = r & 63;
            gtT[blk * (CC * 64) + r] = gt[(b * SS + blk) * CC + k];
        }
    } else {
        int idx = (blk - 64) * 256 + tid;
        h0a[idx] = 0.f; h1a[idx] = 0.f; c0[idx] = 0.f; c1[idx] = 0.f;
        int d = idx >> 6, b = idx & 63;
        float v = Lf[(size_t)b * (T_ * D_) + d];
        ctxT0[idx] = v;
        ctxb0[b * 512 + d] = v;
    }
}

// ---------------- per-step kernels ----------------

// LSTM0: 128 blocks x 4 units (r9-proven, verbatim)
__global__ __launch_bounds__(256) void k_lstm0(
        int s, const float* __restrict__ gtT, const float* __restrict__ ctxT,
        const float* __restrict__ h0in, float* __restrict__ h0out,
        float* __restrict__ c0,
        const float* __restrict__ wih0, const float* __restrict__ whh0,
        const float* __restrict__ bih0, const float* __restrict__ bhh0,
        int* __restrict__ colZero) {
    __shared__ float xs[4096];
    __shared__ float wsm[16 * 68];
    __shared__ float ex[16 * 64];
    int tid = threadIdx.x, uid = blockIdx.x;
    int r = tid >> 4, tb = tid & 15;
    float a0 = 0.f, a1 = 0.f, a2 = 0.f, a3 = 0.f;
    for (int kc = 0; kc < 17; ++kc) {
        int k0 = kc * 64;
        __syncthreads();
#pragma unroll
        for (int i = 0; i < 4; ++i) {
            int e4 = i * 256 + tid;
            int kk = e4 >> 4, b4 = (e4 & 15) * 4;
            int k = k0 + kk;
            float4 v;
            if (k < 63) {
                if (s > 0) v = *(const float4*)&gtT[(s - 1) * 4032 + k * 64 + b4];
                else { float o1 = (k == 0) ? 1.f : 0.f; v = make_float4(o1, o1, o1, o1); }
            } else if (k < 575)  v = *(const float4*)&ctxT[(k - 63) * 64 + b4];
            else if (k < 1087)   v = *(const float4*)&h0in[(k - 575) * 64 + b4];
            else                 v = make_float4(0.f, 0.f, 0.f, 0.f);
            *(float4*)&xs[kk * 64 + b4] = v;
        }
#pragma unroll
        for (int i = 0; i < 4; ++i) {
            int lidx = i * 256 + tid;
            int rr = lidx >> 6, kk = lidx & 63;
            int k = k0 + kk;
            int g2 = rr >> 2, uu = rr & 3;
            int jj = g2 * 512 + uid * 4 + uu;
            float wv;
            if (k < 575)       wv = wih0[(size_t)jj * 575 + k];
            else if (k < 1087) wv = whh0[(size_t)jj * 512 + (k - 575)];
            else               wv = 0.f;
            wsm[rr * 68 + kk] = wv;
        }
        __syncthreads();
        const float* wsr = &wsm[r * 68];
        const float* xsr = &xs[tb * 4];
#pragma unroll
        for (int kk = 0; kk < 64; ++kk) {
            float wv = wsr[kk];
            float4 x4 = *(const float4*)&xsr[kk * 64];
            a0 = fmaf(wv, x4.x, a0);
            a1 = fmaf(wv, x4.y, a1);
            a2 = fmaf(wv, x4.z, a2);
            a3 = fmaf(wv, x4.w, a3);
        }
    }
    {
        int g2 = r >> 2, uu = r & 3;
        int j = g2 * 512 + uid * 4 + uu;
        float bias = bih0[j] + bhh0[j];
        __syncthreads();
        *(float4*)&ex[r * 64 + tb * 4] =
            make_float4(a0 + bias, a1 + bias, a2 + bias, a3 + bias);
    }
    __syncthreads();
    {
        int ui = tid >> 6, b = tid & 63;
        float gi = ex[(0 * 4 + ui) * 64 + b];
        float gf = ex[(1 * 4 + ui) * 64 + b];
        float gg = ex[(2 * 4 + ui) * 64 + b];
        float go = ex[(3 * 4 + ui) * 64 + b];
        int u = uid * 4 + ui;
        float cv = c0[u * 64 + b];
        float cn = sigm(gf) * cv + sigm(gi) * tanhf(gg);
        float hn = sigm(go) * tanhf(cn);
        c0[u * 64 + b] = cn;
        h0out[u * 64 + b] = hn;
    }
    if (uid == 0) {
        for (int i = tid; i < 1024; i += 256) colZero[i] = 1;
    }
}

// LSTM1: 128 blocks x 4 units (r9-proven, verbatim)
__global__ __launch_bounds__(256) void k_lstm1(
        const float* __restrict__ h0cur, const float* __restrict__ h1in,
        float* __restrict__ h1out, float* __restrict__ c1,
        float* __restrict__ h1bout,
        const float* __restrict__ wih1, const float* __restrict__ whh1,
        const float* __restrict__ bih1, const float* __restrict__ bhh1) {
    __shared__ float xs[4096];
    __shared__ float wsm[16 * 68];
    __shared__ float ex[16 * 64];
    int tid = threadIdx.x, uid = blockIdx.x;
    int r = tid >> 4, tb = tid & 15;
    float a0 = 0.f, a1 = 0.f, a2 = 0.f, a3 = 0.f;
    for (int kc = 0; kc < 16; ++kc) {
        int k0 = kc * 64;
        __syncthreads();
#pragma unroll
        for (int i = 0; i < 4; ++i) {
            int e4 = i * 256 + tid;
            int kk = e4 >> 4, b4 = (e4 & 15) * 4;
            int k = k0 + kk;
            float4 v = (k < 512) ? *(const float4*)&h0cur[k * 64 + b4]
                                 : *(const float4*)&h1in[(k - 512) * 64 + b4];
            *(float4*)&xs[kk * 64 + b4] = v;
        }
#pragma unroll
        for (int i = 0; i < 4; ++i) {
            int lidx = i * 256 + tid;
            int rr = lidx >> 6, kk = lidx & 63;
            int k = k0 + kk;
            int g2 = rr >> 2, uu = rr & 3;
            int jj = g2 * 512 + uid * 4 + uu;
            float wv = (k < 512) ? wih1[(size_t)jj * 512 + k]
                                 : whh1[(size_t)jj * 512 + (k - 512)];
            wsm[rr * 68 + kk] = wv;
        }
        __syncthreads();
        const float* wsr = &wsm[r * 68];
        const float* xsr = &xs[tb * 4];
#pragma unroll
        for (int kk = 0; kk < 64; ++kk) {
            float wv = wsr[kk];
            float4 x4 = *(const float4*)&xsr[kk * 64];
            a0 = fmaf(wv, x4.x, a0);
            a1 = fmaf(wv, x4.y, a1);
            a2 = fmaf(wv, x4.z, a2);
            a3 = fmaf(wv, x4.w, a3);
        }
    }
    {
        int g2 = r >> 2, uu = r & 3;
        int j = g2 * 512 + uid * 4 + uu;
        float bias = bih1[j] + bhh1[j];
        __syncthreads();
        *(float4*)&ex[r * 64 + tb * 4] =
            make_float4(a0 + bias, a1 + bias, a2 + bias, a3 + bias);
    }
    __syncthreads();
    {
        int ui = tid >> 6, b = tid & 63;
        float gi = ex[(0 * 4 + ui) * 64 + b];
        float gf = ex[(1 * 4 + ui) * 64 + b];
        float gg = ex[(2 * 4 + ui) * 64 + b];
        float go = ex[(3 * 4 + ui) * 64 + b];
        int u = uid * 4 + ui;
        float cv = c1[u * 64 + b];
        float cn = sigm(gf) * cv + sigm(gi) * tanhf(gg);
        float hn = sigm(go) * tanhf(cn);
        c1[u * 64 + b] = cn;
        h1out[u * 64 + b] = hn;
        h1bout[b * 512 + u] = hn;
    }
}

// phi once (r11-proven, verbatim): cdb[b*256+m] = relu(phib[m] + sum_k h1[k][b]*phiw[m][k])
__global__ __launch_bounds__(256) void k_phi(
        const float* __restrict__ h1u,
        const float* __restrict__ phiw, const float* __restrict__ phib,
        float* __restrict__ cdb) {
    __shared__ float xs[4096];
    __shared__ float wsm[32 * 68];
    int tid = threadIdx.x;
    int m0 = blockIdx.x * 32;
    int mr = tid >> 3, bq = tid & 7;
    float bias = phib[m0 + mr];
    float acc[8] = {bias, bias, bias, bias, bias, bias, bias, bias};
    for (int kc = 0; kc < 8; ++kc) {
        int k0 = kc * 64;
        __syncthreads();
#pragma unroll
        for (int i = 0; i < 4; ++i) {
            int idx4 = i * 256 + tid;
            int kk = idx4 >> 4, b4 = (idx4 & 15) * 4;
            *(float4*)&xs[kk * 64 + b4] = *(const float4*)&h1u[(k0 + kk) * 64 + b4];
        }
#pragma unroll
        for (int i = 0; i < 2; ++i) {
            int idx4 = i * 256 + tid;
            int mm = idx4 >> 4, kk4 = (idx4 & 15) * 4;
            *(float4*)&wsm[mm * 68 + kk4] = *(const float4*)&phiw[(size_t)(m0 + mm) * 512 + k0 + kk4];
        }
        __syncthreads();
        const float* wr = &wsm[mr * 68];
#pragma unroll
        for (int kk = 0; kk < 64; ++kk) {
            float wv = wr[kk];
            const float* xp = &xs[kk * 64 + bq * 8];
#pragma unroll
            for (int j = 0; j < 8; ++j)
                acc[j] = fmaf(xp[j], wv, acc[j]);
        }
    }
#pragma unroll
    for (int j = 0; j < 8; ++j)
        cdb[(bq * 8 + j) * 256 + m0 + mr] = fmaxf(acc[j], 0.f);
}

// energy with bit-exact zero-skip: cd>=0, clT>=0 => all terms >=0, skipping
// cd[m]==0 adds exactly +0.0; ascending-m order preserved by ordered compaction.
__global__ __launch_bounds__(128) void k_energy(
        const float* __restrict__ cdb,
        const unsigned short* __restrict__ clT,
        float* __restrict__ energy_bt, float* __restrict__ energyT,
        int* __restrict__ colZero) {
    __shared__ float cdc[256];
    __shared__ unsigned short midx[256];
    __shared__ int wcnt[4];
    int tid = threadIdx.x;
    int b = blockIdx.x >> 3, tc = blockIdx.x & 7;
    float cA = cdb[b * 256 + tid];
    float cB = cdb[b * 256 + 128 + tid];
    int w = tid >> 6;
    unsigned long long lt = (1ull << (tid & 63)) - 1ull;
    unsigned long long mA = __ballot(cA != 0.f);
    unsigned long long mB = __ballot(cB != 0.f);
    if ((tid & 63) == 0) { wcnt[w] = __popcll(mA); wcnt[2 + w] = __popcll(mB); }
    __syncthreads();
    int offA = (w == 1) ? wcnt[0] : 0;
    int offB = wcnt[0] + wcnt[1] + ((w == 1) ? wcnt[2] : 0);
    int nnz = wcnt[0] + wcnt[1] + wcnt[2] + wcnt[3];
    if (cA != 0.f) { int p = offA + __popcll(mA & lt); cdc[p] = cA; midx[p] = (unsigned short)tid; }
    if (cB != 0.f) { int p = offB + __popcll(mB & lt); cdc[p] = cB; midx[p] = (unsigned short)(tid + 128); }
    __syncthreads();
    int t = tc * 128 + tid;
    float e = 0.f;
    const unsigned short* base = clT + ((size_t)(b * 256)) * 1024 + t;
#pragma unroll 8
    for (int i = 0; i < nnz; ++i)
        e = fmaf(cdc[i], bf2f(base[(size_t)midx[i] * 1024]), e);
    energyT[t * 64 + b] = e;
    energy_bt[b * 1024 + t] = e;
    if (e != 0.f) colZero[t] = 0;
}

// copula column stats (r9-proven, verbatim): 256 blocks x 4 t
__global__ __launch_bounds__(256) void k_cop(
        const float* __restrict__ energyT,
        float* __restrict__ rS, float* __restrict__ dsS, int* __restrict__ badS) {
    int tid = threadIdx.x;
    int wv = tid >> 6, b = tid & 63;
    int t = blockIdx.x * 4 + wv;
    if (t >= 1 && t < 1023) {
        float e = energyT[t * 64 + b];
        float a = energyT[(t - 1) * 64 + b];
        float ma = wsum64(a) * (1.f / 64.f);
        float mb = wsum64(e) * (1.f / 64.f);
        float am = a - ma, bm = e - mb;
        float sab = wsum64(am * bm);
        float saa = wsum64(am * am);
        float sbb = wsum64(bm * bm);
        int aeq = __all(a == e);
        float r = sab / sqrtf(saa * sbb + 1e-12f);
        float det = 1.f - r * r;
        int bad = (det < 0.01f || aeq) ? 1 : 0;
        float ds = fmaxf(det, 1e-6f);
        if (b == 0) { rS[t] = r; dsS[t] = ds; badS[t] = bad; }
    }
}

// fused vals+softmax+atts+context (+charpred for prow on dq==0): 512 blocks (r10-proven)
__global__ __launch_bounds__(256) void k_softctx(
        int doSM, int s, int prow,
        const float* __restrict__ energy_bt, const int* __restrict__ colZero,
        const float* __restrict__ rS, const float* __restrict__ dsS,
        const int* __restrict__ badS,
        const unsigned short* __restrict__ Lbf,
        const float* __restrict__ h1bp, const float* __restrict__ ctxb_prev,
        const float* __restrict__ charw, const float* __restrict__ charb,
        float* __restrict__ ctxT_next, float* __restrict__ ctxb_next,
        float* __restrict__ preds, float* __restrict__ atts) {
    __shared__ float e_l[1024];
    __shared__ float red[256];
    __shared__ int zred[256];
    __shared__ float att[1056];
    __shared__ float red2[256];
    __shared__ float lgs[64];
    int tid = threadIdx.x;
    int b = blockIdx.x >> 3, dq = blockIdx.x & 7, d0 = dq * 64;

    if (doSM) {
        *(float4*)&e_l[tid * 4] = *(const float4*)&energy_bt[b * 1024 + tid * 4];
        int z = colZero[tid] | colZero[256 + tid] | colZero[512 + tid] | colZero[768 + tid];
        zred[tid] = z;
        __syncthreads();
        for (int o = 128; o > 0; o >>= 1) {
            if (tid < o) zred[tid] |= zred[tid + o];
            __syncthreads();
        }
        int zf = zred[0];
        float4 rv = *(const float4*)&rS[tid * 4];
        float4 dv = *(const float4*)&dsS[tid * 4];
        int4 bv = *(const int4*)&badS[tid * 4];
        float rvv[4] = {rv.x, rv.y, rv.z, rv.w};
        float dvv[4] = {dv.x, dv.y, dv.z, dv.w};
        int bvv[4] = {bv.x, bv.y, bv.z, bv.w};
        float vals[4];
#pragma unroll
        for (int i = 0; i < 4; ++i) {
            int t = tid * 4 + i;
            float e = e_l[t];
            if (zf) {
                vals[i] = e;
            } else {
                float cp;
                if (t == 0 || t == 1023) cp = 1.f;
                else if (bvv[i]) cp = 10.f;
                else {
                    float a = e_l[t - 1];
                    float r = rvv[i], ds = dvv[i];
                    float quad = r * r * (a * a + e * e) - 2.f * r * a * e;
                    cp = __expf(-0.5f * quad / ds) / sqrtf(ds);
                }
                vals[i] = __expf(-0.5f * e * e) * INV_SQRT_2PI * cp;
            }
        }
        float lm = fmaxf(fmaxf(vals[0], vals[1]), fmaxf(vals[2], vals[3]));
        red[tid] = lm;
        __syncthreads();
        for (int o = 128; o > 0; o >>= 1) {
            if (tid < o) red[tid] = fmaxf(red[tid], red[tid + o]);
            __syncthreads();
        }
        float M = red[0];
        __syncthreads();
        float e0 = __expf(vals[0] - M), e1 = __expf(vals[1] - M);
        float e2 = __expf(vals[2] - M), e3 = __expf(vals[3] - M);
        red[tid] = e0 + e1 + e2 + e3;
        __syncthreads();
        for (int o = 128; o > 0; o >>= 1) {
            if (tid < o) red[tid] += red[tid + o];
            __syncthreads();
        }
        float inv = 1.f / red[0];
        float4 a4 = make_float4(e0 * inv, e1 * inv, e2 * inv, e3 * inv);
        {
            int t4 = tid * 4;
            int pk = t4 + (t4 >> 5);
            att[pk] = a4.x; att[pk + 1] = a4.y; att[pk + 2] = a4.z; att[pk + 3] = a4.w;
        }
        if (dq == 0)
            *(float4*)&atts[((size_t)s * B_ + b) * 1024 + tid * 4] = a4;
        __syncthreads();

        int tc = tid >> 3, dg = tid & 7;
        const unsigned short* Lb = Lbf + (size_t)b * 524288 + (size_t)tc * 32 * 512 + d0 + dg * 8;
        float acc[8] = {0.f, 0.f, 0.f, 0.f, 0.f, 0.f, 0.f, 0.f};
#pragma unroll
        for (int i = 0; i < 32; ++i) {
            float wv = att[tc * 33 + i];
            short8v v = *(const short8v*)(Lb + (size_t)i * 512);
            acc[0] = fmaf(wv, bf2f((unsigned short)v[0]), acc[0]);
            acc[1] = fmaf(wv, bf2f((unsigned short)v[1]), acc[1]);
            acc[2] = fmaf(wv, bf2f((unsigned short)v[2]), acc[2]);
            acc[3] = fmaf(wv, bf2f((unsigned short)v[3]), acc[3]);
            acc[4] = fmaf(wv, bf2f((unsigned short)v[4]), acc[4]);
            acc[5] = fmaf(wv, bf2f((unsigned short)v[5]), acc[5]);
            acc[6] = fmaf(wv, bf2f((unsigned short)v[6]), acc[6]);
            acc[7] = fmaf(wv, bf2f((unsigned short)v[7]), acc[7]);
        }
#pragma unroll
        for (int j = 0; j < 8; ++j) {
            acc[j] += __shfl_xor(acc[j], 8, 64);
            acc[j] += __shfl_xor(acc[j], 16, 64);
            acc[j] += __shfl_xor(acc[j], 32, 64);
        }
        int w = tid >> 6;
        if ((tid & 56) == 0) {
#pragma unroll
            for (int j = 0; j < 8; ++j) red2[w * 64 + dg * 8 + j] = acc[j];
        }
        __syncthreads();
        if (tid < 64) {
            float cv = red2[tid] + red2[64 + tid] + red2[128 + tid] + red2[192 + tid];
            ctxT_next[(d0 + tid) * 64 + b] = cv;
            ctxb_next[b * 512 + d0 + tid] = cv;
        }
    }

    if (prow >= 0 && dq == 0) {
        __syncthreads();
        float* cpx = e_l;
        for (int i = tid; i < 1024; i += 256)
            cpx[i] = (i < 512) ? h1bp[b * 512 + i] : ctxb_prev[b * 512 + (i - 512)];
        __syncthreads();
        int c = tid >> 2, kl = tid & 3;
        float p = 0.f;
        if (c < 63) {
            const float4* cw = (const float4*)&charw[(size_t)c * 1024 + kl * 256];
            const float4* cx = (const float4*)&cpx[kl * 256];
#pragma unroll
            for (int q = 0; q < 64; ++q) {
                float4 w4 = cw[q], x4 = cx[q];
                p = fmaf(x4.x, w4.x, p); p = fmaf(x4.y, w4.y, p);
                p = fmaf(x4.z, w4.z, p); p = fmaf(x4.w, w4.w, p);
            }
        }
        p += __shfl_xor(p, 1, 64); p += __shfl_xor(p, 2, 64);
        if (kl == 0 && c < 63) lgs[c] = p + charb[c];
        if (tid == 0) lgs[63] = -1e30f;
        __syncthreads();
        if (tid < 64) {
            float lg = (tid < 63) ? lgs[tid] : -1e30f;
            float mx = lg;
            for (int o = 32; o > 0; o >>= 1) mx = fmaxf(mx, __shfl_xor(mx, o, 64));
            float ex2 = (tid < 63) ? __expf(lg - mx) : 0.f;
            float sume = wsum64(ex2);
            if (tid < 63)
                preds[((size_t)prow * B_ + b) * CC + tid] = lg - mx - __logf(sume);
        }
    }
}

extern "C" void kernel_launch(void* const* d_in, const int* in_sizes, int n_in,
                              void* d_out, int out_size, void* d_ws, size_t ws_size,
                              hipStream_t stream) {
    const float* Lf   = (const float*)d_in[0];
    const float* gt   = (const float*)d_in[1];
    const float* phiw = (const float*)d_in[2];
    const float* phib = (const float*)d_in[3];
    const float* psiw = (const float*)d_in[4];
    const float* psib = (const float*)d_in[5];
    const float* wih0 = (const float*)d_in[6];
    const float* whh0 = (const float*)d_in[7];
    const float* bih0 = (const float*)d_in[8];
    const float* bhh0 = (const float*)d_in[9];
    const float* wih1 = (const float*)d_in[10];
    const float* whh1 = (const float*)d_in[11];
    const float* bih1 = (const float*)d_in[12];
    const float* bhh1 = (const float*)d_in[13];
    const float* charw = (const float*)d_in[14];
    const float* charb = (const float*)d_in[15];

    float* preds = (float*)d_out;
    float* atts  = (float*)d_out + (size_t)SS * B_ * CC;

    char* ws = (char*)d_ws;
    size_t off = 0;
    auto alloc = [&](size_t bytes) { size_t o = off; off = (off + bytes + 255) & ~(size_t)255; return o; };
    unsigned short* clT = (unsigned short*)(ws + alloc((size_t)B_ * M_ * T_ * 2));
    unsigned short* Lbf = (unsigned short*)(ws + alloc((size_t)B_ * T_ * D_ * 2));
    unsigned short* psibf = (unsigned short*)(ws + alloc((size_t)M_ * D_ * 2));
    float* gtT      = (float*)(ws + alloc((size_t)SS * CC * 64 * 4));
    float* h0p0     = (float*)(ws + alloc(H_ * B_ * 4));
    float* h0p1     = (float*)(ws + alloc(H_ * B_ * 4));
    float* h1p0     = (float*)(ws + alloc(H_ * B_ * 4));
    float* h1p1     = (float*)(ws + alloc(H_ * B_ * 4));
    float* hb0      = (float*)(ws + alloc(H_ * B_ * 4));
    float* hb1      = (float*)(ws + alloc(H_ * B_ * 4));
    float* c0       = (float*)(ws + alloc(H_ * B_ * 4));
    float* c1       = (float*)(ws + alloc(H_ * B_ * 4));
    float* ctxT0    = (float*)(ws + alloc(H_ * B_ * 4));
    float* ctxT1    = (float*)(ws + alloc(H_ * B_ * 4));
    float* ctxb0    = (float*)(ws + alloc(H_ * B_ * 4));
    float* ctxb1    = (float*)(ws + alloc(H_ * B_ * 4));
    float* cdb      = (float*)(ws + alloc(B_ * M_ * 4));
    float* energy_bt = (float*)(ws + alloc(B_ * T_ * 4));
    float* energyT   = (float*)(ws + alloc(B_ * T_ * 4));
    float* rS       = (float*)(ws + alloc(T_ * 4));
    float* dsS      = (float*)(ws + alloc(T_ * 4));
    int* badS       = (int*)(ws + alloc(T_ * 4));
    int* colZero    = (int*)(ws + alloc(T_ * 4));

    k_conv<<<2048, 256, 0, stream>>>(Lf, Lbf, (B_ * T_ * D_) / 4);
    k_conv<<<128, 256, 0, stream>>>(psiw, psibf, (M_ * D_) / 4);
    k_gemm_mfma<<<4096, 256, 0, stream>>>(Lbf, psibf, psib, clT);
    k_init<<<192, 256, 0, stream>>>(Lf, gt, gtT, h0p0, h1p0, c0, c1, ctxT0, ctxb0);

    float* h0p[2] = {h0p0, h0p1};
    float* h1p[2] = {h1p0, h1p1};
    float* hb[2]  = {hb0, hb1};
    float* ctxTb[2] = {ctxT0, ctxT1};
    float* ctxbb[2] = {ctxb0, ctxb1};
    for (int s = 0; s < SS; ++s) {
        int pi = s & 1, po = pi ^ 1;
        k_lstm0<<<128, 256, 0, stream>>>(s, gtT, ctxTb[pi], h0p[pi], h0p[po], c0,
                                         wih0, whh0, bih0, bhh0, colZero);
        k_lstm1<<<128, 256, 0, stream>>>(h0p[po], h1p[pi], h1p[po], c1, hb[pi],
                                         wih1, whh1, bih1, bhh1);
        k_phi<<<8, 256, 0, stream>>>(h1p[po], phiw, phib, cdb);
        k_energy<<<512, 128, 0, stream>>>(cdb, clT, energy_bt, energyT, colZero);
        k_cop<<<256, 256, 0, stream>>>(energyT, rS, dsS, badS);
        k_softctx<<<512, 256, 0, stream>>>(1, s, s - 1, energy_bt, colZero,
                                           rS, dsS, badS, Lbf,
                                           hb[po], ctxbb[pi], charw, charb,
                                           ctxTb[po], ctxbb[po], preds, atts);
    }
    // tail: charpred + preds for step 63 (h1b(63)=hb[1], ctx(63)=bufs[0])
    k_softctx<<<512, 256, 0, stream>>>(0, SS - 1, SS - 1, energy_bt, colZero,
                                       rS, dsS, badS, Lbf,
                                       hb[1], ctxbb[0], charw, charb,
                                       ctxTb[1], ctxbb[1], preds, atts);
}

// Round 13
// 9125.100 us; speedup vs baseline: 1.0142x; 1.0142x over previous
//
#include <hip/hip_runtime.h>
#include <hip/hip_bf16.h>
#include <math.h>

#define B_ 64
#define T_ 1024
#define D_ 512
#define H_ 512
#define M_ 256
#define CC 63
#define SS 64
#define INV_SQRT_2PI 0.3989422804014327f

typedef __attribute__((ext_vector_type(8))) short short8v;
typedef __attribute__((ext_vector_type(4))) float f32x4;

static __device__ __forceinline__ float bf2f(unsigned short u) {
    unsigned int x = ((unsigned int)u) << 16;
    return __uint_as_float(x);
}
static __device__ __forceinline__ unsigned short f2bf(float f) {
    unsigned int x = __float_as_uint(f);
    unsigned int r = (x + 0x7fff + ((x >> 16) & 1)) >> 16;
    return (unsigned short)r;
}
static __device__ __forceinline__ float sigm(float x) {
    return 1.f / (1.f + __expf(-x));
}
static __device__ __forceinline__ float wsum64(float v) {
    for (int o = 32; o > 0; o >>= 1) v += __shfl_xor(v, o, 64);
    return v;
}

// ---------------- prologue ----------------

__global__ __launch_bounds__(256) void k_conv(const float* __restrict__ src,
        unsigned short* __restrict__ dst, int n4) {
    int stride = gridDim.x * 256;
    for (int i = blockIdx.x * 256 + threadIdx.x; i < n4; i += stride) {
        float4 v = ((const float4*)src)[i];
        ushort4 o;
        o.x = f2bf(v.x); o.y = f2bf(v.y); o.z = f2bf(v.z); o.w = f2bf(v.w);
        ((ushort4*)dst)[i] = o;
    }
}

// MFMA bf16 GEMM (r2-proven): clT[b*256+m][t] = bf16(relu(Lbf x psibf^T + psib))
__global__ __launch_bounds__(256) void k_gemm_mfma(
        const unsigned short* __restrict__ Abf,
        const unsigned short* __restrict__ Bbf,
        const float* __restrict__ psib,
        unsigned short* __restrict__ clT) {
    __shared__ unsigned short As[64 * 40];
    __shared__ unsigned short Bs[64 * 40];
    __shared__ unsigned short Os[64 * 72];
    int tid = threadIdx.x;
    int p0 = (blockIdx.x >> 2) * 64;
    int m0 = (blockIdx.x & 3) * 64;
    int w = tid >> 6, l = tid & 63;
    int wp = (w & 1) * 32, wm = (w >> 1) * 32;
    f32x4 acc[2][2] = {};
    int srow = tid >> 2, sc = (tid & 3) * 8;
    for (int k0 = 0; k0 < 512; k0 += 32) {
        __syncthreads();
        *(short8v*)&As[srow * 40 + sc] = *(const short8v*)&Abf[(size_t)(p0 + srow) * 512 + k0 + sc];
        *(short8v*)&Bs[srow * 40 + sc] = *(const short8v*)&Bbf[(size_t)(m0 + srow) * 512 + k0 + sc];
        __syncthreads();
        int koff = (l >> 4) * 8;
        int rlo = l & 15;
        short8v a0 = *(short8v*)&As[(wp + rlo) * 40 + koff];
        short8v a1 = *(short8v*)&As[(wp + 16 + rlo) * 40 + koff];
        short8v b0 = *(short8v*)&Bs[(wm + rlo) * 40 + koff];
        short8v b1 = *(short8v*)&Bs[(wm + 16 + rlo) * 40 + koff];
        acc[0][0] = __builtin_amdgcn_mfma_f32_16x16x32_bf16(a0, b0, acc[0][0], 0, 0, 0);
        acc[0][1] = __builtin_amdgcn_mfma_f32_16x16x32_bf16(a0, b1, acc[0][1], 0, 0, 0);
        acc[1][0] = __builtin_amdgcn_mfma_f32_16x16x32_bf16(a1, b0, acc[1][0], 0, 0, 0);
        acc[1][1] = __builtin_amdgcn_mfma_f32_16x16x32_bf16(a1, b1, acc[1][1], 0, 0, 0);
    }
    __syncthreads();
#pragma unroll
    for (int pi = 0; pi < 2; ++pi)
#pragma unroll
        for (int mi = 0; mi < 2; ++mi)
#pragma unroll
            for (int r = 0; r < 4; ++r) {
                int tl = wp + pi * 16 + (l >> 4) * 4 + r;
                int ml = wm + mi * 16 + (l & 15);
                float v = fmaxf(acc[pi][mi][r] + psib[m0 + ml], 0.f);
                Os[ml * 72 + tl] = f2bf(v);
            }
    __syncthreads();
    int b = p0 >> 10, t0 = p0 & 1023;
    int mm = tid >> 2, c16 = (tid & 3) * 16;
    short8v v0 = *(short8v*)&Os[mm * 72 + c16];
    short8v v1 = *(short8v*)&Os[mm * 72 + c16 + 8];
    size_t base = ((size_t)(b * 256 + m0 + mm)) * 1024 + t0 + c16;
    *(short8v*)&clT[base] = v0;
    *(short8v*)&clT[base + 8] = v1;
}

__global__ __launch_bounds__(256) void k_init(const float* __restrict__ Lf,
        const float* __restrict__ gt,
        float* gtT, float* h0a, float* h1a, float* c0, float* c1,
        float* ctxT0, float* ctxb0) {
    int tid = threadIdx.x, blk = blockIdx.x;
    if (blk < 64) {
        for (int r = tid; r < CC * 64; r += 256) {
            int k = r >> 6, b = r & 63;
            gtT[blk * (CC * 64) + r] = gt[(b * SS + blk) * CC + k];
        }
    } else {
        int idx = (blk - 64) * 256 + tid;
        h0a[idx] = 0.f; h1a[idx] = 0.f; c0[idx] = 0.f; c1[idx] = 0.f;
        int d = idx >> 6, b = idx & 63;
        float v = Lf[(size_t)b * (T_ * D_) + d];
        ctxT0[idx] = v;
        ctxb0[b * 512 + d] = v;
    }
}

// ---------------- per-step kernels ----------------

// LSTM0: 128 blocks x 4 units (r9-proven, verbatim)
__global__ __launch_bounds__(256) void k_lstm0(
        int s, const float* __restrict__ gtT, const float* __restrict__ ctxT,
        const float* __restrict__ h0in, float* __restrict__ h0out,
        float* __restrict__ c0,
        const float* __restrict__ wih0, const float* __restrict__ whh0,
        const float* __restrict__ bih0, const float* __restrict__ bhh0,
        int* __restrict__ colZero) {
    __shared__ float xs[4096];
    __shared__ float wsm[16 * 68];
    __shared__ float ex[16 * 64];
    int tid = threadIdx.x, uid = blockIdx.x;
    int r = tid >> 4, tb = tid & 15;
    float a0 = 0.f, a1 = 0.f, a2 = 0.f, a3 = 0.f;
    for (int kc = 0; kc < 17; ++kc) {
        int k0 = kc * 64;
        __syncthreads();
#pragma unroll
        for (int i = 0; i < 4; ++i) {
            int e4 = i * 256 + tid;
            int kk = e4 >> 4, b4 = (e4 & 15) * 4;
            int k = k0 + kk;
            float4 v;
            if (k < 63) {
                if (s > 0) v = *(const float4*)&gtT[(s - 1) * 4032 + k * 64 + b4];
                else { float o1 = (k == 0) ? 1.f : 0.f; v = make_float4(o1, o1, o1, o1); }
            } else if (k < 575)  v = *(const float4*)&ctxT[(k - 63) * 64 + b4];
            else if (k < 1087)   v = *(const float4*)&h0in[(k - 575) * 64 + b4];
            else                 v = make_float4(0.f, 0.f, 0.f, 0.f);
            *(float4*)&xs[kk * 64 + b4] = v;
        }
#pragma unroll
        for (int i = 0; i < 4; ++i) {
            int lidx = i * 256 + tid;
            int rr = lidx >> 6, kk = lidx & 63;
            int k = k0 + kk;
            int g2 = rr >> 2, uu = rr & 3;
            int jj = g2 * 512 + uid * 4 + uu;
            float wv;
            if (k < 575)       wv = wih0[(size_t)jj * 575 + k];
            else if (k < 1087) wv = whh0[(size_t)jj * 512 + (k - 575)];
            else               wv = 0.f;
            wsm[rr * 68 + kk] = wv;
        }
        __syncthreads();
        const float* wsr = &wsm[r * 68];
        const float* xsr = &xs[tb * 4];
#pragma unroll
        for (int kk = 0; kk < 64; ++kk) {
            float wv = wsr[kk];
            float4 x4 = *(const float4*)&xsr[kk * 64];
            a0 = fmaf(wv, x4.x, a0);
            a1 = fmaf(wv, x4.y, a1);
            a2 = fmaf(wv, x4.z, a2);
            a3 = fmaf(wv, x4.w, a3);
        }
    }
    {
        int g2 = r >> 2, uu = r & 3;
        int j = g2 * 512 + uid * 4 + uu;
        float bias = bih0[j] + bhh0[j];
        __syncthreads();
        *(float4*)&ex[r * 64 + tb * 4] =
            make_float4(a0 + bias, a1 + bias, a2 + bias, a3 + bias);
    }
    __syncthreads();
    {
        int ui = tid >> 6, b = tid & 63;
        float gi = ex[(0 * 4 + ui) * 64 + b];
        float gf = ex[(1 * 4 + ui) * 64 + b];
        float gg = ex[(2 * 4 + ui) * 64 + b];
        float go = ex[(3 * 4 + ui) * 64 + b];
        int u = uid * 4 + ui;
        float cv = c0[u * 64 + b];
        float cn = sigm(gf) * cv + sigm(gi) * tanhf(gg);
        float hn = sigm(go) * tanhf(cn);
        c0[u * 64 + b] = cn;
        h0out[u * 64 + b] = hn;
    }
    if (uid == 0) {
        for (int i = tid; i < 1024; i += 256) colZero[i] = 1;
    }
}

// LSTM1: 128 blocks x 4 units (r9-proven, verbatim)
__global__ __launch_bounds__(256) void k_lstm1(
        const float* __restrict__ h0cur, const float* __restrict__ h1in,
        float* __restrict__ h1out, float* __restrict__ c1,
        float* __restrict__ h1bout,
        const float* __restrict__ wih1, const float* __restrict__ whh1,
        const float* __restrict__ bih1, const float* __restrict__ bhh1) {
    __shared__ float xs[4096];
    __shared__ float wsm[16 * 68];
    __shared__ float ex[16 * 64];
    int tid = threadIdx.x, uid = blockIdx.x;
    int r = tid >> 4, tb = tid & 15;
    float a0 = 0.f, a1 = 0.f, a2 = 0.f, a3 = 0.f;
    for (int kc = 0; kc < 16; ++kc) {
        int k0 = kc * 64;
        __syncthreads();
#pragma unroll
        for (int i = 0; i < 4; ++i) {
            int e4 = i * 256 + tid;
            int kk = e4 >> 4, b4 = (e4 & 15) * 4;
            int k = k0 + kk;
            float4 v = (k < 512) ? *(const float4*)&h0cur[k * 64 + b4]
                                 : *(const float4*)&h1in[(k - 512) * 64 + b4];
            *(float4*)&xs[kk * 64 + b4] = v;
        }
#pragma unroll
        for (int i = 0; i < 4; ++i) {
            int lidx = i * 256 + tid;
            int rr = lidx >> 6, kk = lidx & 63;
            int k = k0 + kk;
            int g2 = rr >> 2, uu = rr & 3;
            int jj = g2 * 512 + uid * 4 + uu;
            float wv = (k < 512) ? wih1[(size_t)jj * 512 + k]
                                 : whh1[(size_t)jj * 512 + (k - 512)];
            wsm[rr * 68 + kk] = wv;
        }
        __syncthreads();
        const float* wsr = &wsm[r * 68];
        const float* xsr = &xs[tb * 4];
#pragma unroll
        for (int kk = 0; kk < 64; ++kk) {
            float wv = wsr[kk];
            float4 x4 = *(const float4*)&xsr[kk * 64];
            a0 = fmaf(wv, x4.x, a0);
            a1 = fmaf(wv, x4.y, a1);
            a2 = fmaf(wv, x4.z, a2);
            a3 = fmaf(wv, x4.w, a3);
        }
    }
    {
        int g2 = r >> 2, uu = r & 3;
        int j = g2 * 512 + uid * 4 + uu;
        float bias = bih1[j] + bhh1[j];
        __syncthreads();
        *(float4*)&ex[r * 64 + tb * 4] =
            make_float4(a0 + bias, a1 + bias, a2 + bias, a3 + bias);
    }
    __syncthreads();
    {
        int ui = tid >> 6, b = tid & 63;
        float gi = ex[(0 * 4 + ui) * 64 + b];
        float gf = ex[(1 * 4 + ui) * 64 + b];
        float gg = ex[(2 * 4 + ui) * 64 + b];
        float go = ex[(3 * 4 + ui) * 64 + b];
        int u = uid * 4 + ui;
        float cv = c1[u * 64 + b];
        float cn = sigm(gf) * cv + sigm(gi) * tanhf(gg);
        float hn = sigm(go) * tanhf(cn);
        c1[u * 64 + b] = cn;
        h1out[u * 64 + b] = hn;
        h1bout[b * 512 + u] = hn;
    }
}

// phi once (r11-proven, verbatim): cdb[b*256+m] = relu(phib[m] + sum_k h1[k][b]*phiw[m][k])
__global__ __launch_bounds__(256) void k_phi(
        const float* __restrict__ h1u,
        const float* __restrict__ phiw, const float* __restrict__ phib,
        float* __restrict__ cdb) {
    __shared__ float xs[4096];
    __shared__ float wsm[32 * 68];
    int tid = threadIdx.x;
    int m0 = blockIdx.x * 32;
    int mr = tid >> 3, bq = tid & 7;
    float bias = phib[m0 + mr];
    float acc[8] = {bias, bias, bias, bias, bias, bias, bias, bias};
    for (int kc = 0; kc < 8; ++kc) {
        int k0 = kc * 64;
        __syncthreads();
#pragma unroll
        for (int i = 0; i < 4; ++i) {
            int idx4 = i * 256 + tid;
            int kk = idx4 >> 4, b4 = (idx4 & 15) * 4;
            *(float4*)&xs[kk * 64 + b4] = *(const float4*)&h1u[(k0 + kk) * 64 + b4];
        }
#pragma unroll
        for (int i = 0; i < 2; ++i) {
            int idx4 = i * 256 + tid;
            int mm = idx4 >> 4, kk4 = (idx4 & 15) * 4;
            *(float4*)&wsm[mm * 68 + kk4] = *(const float4*)&phiw[(size_t)(m0 + mm) * 512 + k0 + kk4];
        }
        __syncthreads();
        const float* wr = &wsm[mr * 68];
#pragma unroll
        for (int kk = 0; kk < 64; ++kk) {
            float wv = wr[kk];
            const float* xp = &xs[kk * 64 + bq * 8];
#pragma unroll
            for (int j = 0; j < 8; ++j)
                acc[j] = fmaf(xp[j], wv, acc[j]);
        }
    }
#pragma unroll
    for (int j = 0; j < 8; ++j)
        cdb[(bq * 8 + j) * 256 + m0 + mr] = fmaxf(acc[j], 0.f);
}

// energy pure stream (r11-proven, verbatim): 512 blocks x 128 thr; dense unroll-16
__global__ __launch_bounds__(128) void k_energy(
        const float* __restrict__ cdb,
        const unsigned short* __restrict__ clT,
        float* __restrict__ energy_bt, float* __restrict__ energyT,
        int* __restrict__ colZero) {
    __shared__ float cdl[256];
    int tid = threadIdx.x;
    int b = blockIdx.x >> 3, tc = blockIdx.x & 7;
    cdl[tid] = cdb[b * 256 + tid];
    cdl[128 + tid] = cdb[b * 256 + 128 + tid];
    __syncthreads();
    int t = tc * 128 + tid;
    float e = 0.f;
    const unsigned short* base = clT + ((size_t)(b * 256)) * 1024 + t;
#pragma unroll 16
    for (int m = 0; m < 256; ++m)
        e = fmaf(cdl[m], bf2f(base[(size_t)m * 1024]), e);
    energyT[t * 64 + b] = e;
    energy_bt[b * 1024 + t] = e;
    if (e != 0.f) colZero[t] = 0;
}

// copula column stats (r9-proven, verbatim): 256 blocks x 4 t
__global__ __launch_bounds__(256) void k_cop(
        const float* __restrict__ energyT,
        float* __restrict__ rS, float* __restrict__ dsS, int* __restrict__ badS) {
    int tid = threadIdx.x;
    int wv = tid >> 6, b = tid & 63;
    int t = blockIdx.x * 4 + wv;
    if (t >= 1 && t < 1023) {
        float e = energyT[t * 64 + b];
        float a = energyT[(t - 1) * 64 + b];
        float ma = wsum64(a) * (1.f / 64.f);
        float mb = wsum64(e) * (1.f / 64.f);
        float am = a - ma, bm = e - mb;
        float sab = wsum64(am * bm);
        float saa = wsum64(am * am);
        float sbb = wsum64(bm * bm);
        int aeq = __all(a == e);
        float r = sab / sqrtf(saa * sbb + 1e-12f);
        float det = 1.f - r * r;
        int bad = (det < 0.01f || aeq) ? 1 : 0;
        float ds = fmaxf(det, 1e-6f);
        if (b == 0) { rS[t] = r; dsS[t] = ds; badS[t] = bad; }
    }
}

// fused vals+softmax+atts+context (+charpred for prow on dq==0): 512 blocks (r10/r12-proven)
__global__ __launch_bounds__(256) void k_softctx(
        int doSM, int s, int prow,
        const float* __restrict__ energy_bt, const int* __restrict__ colZero,
        const float* __restrict__ rS, const float* __restrict__ dsS,
        const int* __restrict__ badS,
        const unsigned short* __restrict__ Lbf,
        const float* __restrict__ h1bp, const float* __restrict__ ctxb_prev,
        const float* __restrict__ charw, const float* __restrict__ charb,
        float* __restrict__ ctxT_next, float* __restrict__ ctxb_next,
        float* __restrict__ preds, float* __restrict__ atts) {
    __shared__ float e_l[1024];
    __shared__ float red[256];
    __shared__ int zred[256];
    __shared__ float att[1056];
    __shared__ float red2[256];
    __shared__ float lgs[64];
    int tid = threadIdx.x;
    int b = blockIdx.x >> 3, dq = blockIdx.x & 7, d0 = dq * 64;

    if (doSM) {
        *(float4*)&e_l[tid * 4] = *(const float4*)&energy_bt[b * 1024 + tid * 4];
        int z = colZero[tid] | colZero[256 + tid] | colZero[512 + tid] | colZero[768 + tid];
        zred[tid] = z;
        __syncthreads();
        for (int o = 128; o > 0; o >>= 1) {
            if (tid < o) zred[tid] |= zred[tid + o];
            __syncthreads();
        }
        int zf = zred[0];
        float4 rv = *(const float4*)&rS[tid * 4];
        float4 dv = *(const float4*)&dsS[tid * 4];
        int4 bv = *(const int4*)&badS[tid * 4];
        float rvv[4] = {rv.x, rv.y, rv.z, rv.w};
        float dvv[4] = {dv.x, dv.y, dv.z, dv.w};
        int bvv[4] = {bv.x, bv.y, bv.z, bv.w};
        float vals[4];
#pragma unroll
        for (int i = 0; i < 4; ++i) {
            int t = tid * 4 + i;
            float e = e_l[t];
            if (zf) {
                vals[i] = e;
            } else {
                float cp;
                if (t == 0 || t == 1023) cp = 1.f;
                else if (bvv[i]) cp = 10.f;
                else {
                    float a = e_l[t - 1];
                    float r = rvv[i], ds = dvv[i];
                    float quad = r * r * (a * a + e * e) - 2.f * r * a * e;
                    cp = __expf(-0.5f * quad / ds) / sqrtf(ds);
                }
                vals[i] = __expf(-0.5f * e * e) * INV_SQRT_2PI * cp;
            }
        }
        float lm = fmaxf(fmaxf(vals[0], vals[1]), fmaxf(vals[2], vals[3]));
        red[tid] = lm;
        __syncthreads();
        for (int o = 128; o > 0; o >>= 1) {
            if (tid < o) red[tid] = fmaxf(red[tid], red[tid + o]);
            __syncthreads();
        }
        float M = red[0];
        __syncthreads();
        float e0 = __expf(vals[0] - M), e1 = __expf(vals[1] - M);
        float e2 = __expf(vals[2] - M), e3 = __expf(vals[3] - M);
        red[tid] = e0 + e1 + e2 + e3;
        __syncthreads();
        for (int o = 128; o > 0; o >>= 1) {
            if (tid < o) red[tid] += red[tid + o];
            __syncthreads();
        }
        float inv = 1.f / red[0];
        float4 a4 = make_float4(e0 * inv, e1 * inv, e2 * inv, e3 * inv);
        {
            int t4 = tid * 4;
            int pk = t4 + (t4 >> 5);
            att[pk] = a4.x; att[pk + 1] = a4.y; att[pk + 2] = a4.z; att[pk + 3] = a4.w;
        }
        if (dq == 0)
            *(float4*)&atts[((size_t)s * B_ + b) * 1024 + tid * 4] = a4;
        __syncthreads();

        int tc = tid >> 3, dg = tid & 7;
        const unsigned short* Lb = Lbf + (size_t)b * 524288 + (size_t)tc * 32 * 512 + d0 + dg * 8;
        float acc[8] = {0.f, 0.f, 0.f, 0.f, 0.f, 0.f, 0.f, 0.f};
#pragma unroll
        for (int i = 0; i < 32; ++i) {
            float wv = att[tc * 33 + i];
            short8v v = *(const short8v*)(Lb + (size_t)i * 512);
            acc[0] = fmaf(wv, bf2f((unsigned short)v[0]), acc[0]);
            acc[1] = fmaf(wv, bf2f((unsigned short)v[1]), acc[1]);
            acc[2] = fmaf(wv, bf2f((unsigned short)v[2]), acc[2]);
            acc[3] = fmaf(wv, bf2f((unsigned short)v[3]), acc[3]);
            acc[4] = fmaf(wv, bf2f((unsigned short)v[4]), acc[4]);
            acc[5] = fmaf(wv, bf2f((unsigned short)v[5]), acc[5]);
            acc[6] = fmaf(wv, bf2f((unsigned short)v[6]), acc[6]);
            acc[7] = fmaf(wv, bf2f((unsigned short)v[7]), acc[7]);
        }
#pragma unroll
        for (int j = 0; j < 8; ++j) {
            acc[j] += __shfl_xor(acc[j], 8, 64);
            acc[j] += __shfl_xor(acc[j], 16, 64);
            acc[j] += __shfl_xor(acc[j], 32, 64);
        }
        int w = tid >> 6;
        if ((tid & 56) == 0) {
#pragma unroll
            for (int j = 0; j < 8; ++j) red2[w * 64 + dg * 8 + j] = acc[j];
        }
        __syncthreads();
        if (tid < 64) {
            float cv = red2[tid] + red2[64 + tid] + red2[128 + tid] + red2[192 + tid];
            ctxT_next[(d0 + tid) * 64 + b] = cv;
            ctxb_next[b * 512 + d0 + tid] = cv;
        }
    }

    if (prow >= 0 && dq == 0) {
        __syncthreads();
        float* cpx = e_l;
        for (int i = tid; i < 1024; i += 256)
            cpx[i] = (i < 512) ? h1bp[b * 512 + i] : ctxb_prev[b * 512 + (i - 512)];
        __syncthreads();
        int c = tid >> 2, kl = tid & 3;
        float p = 0.f;
        if (c < 63) {
            const float4* cw = (const float4*)&charw[(size_t)c * 1024 + kl * 256];
            const float4* cx = (const float4*)&cpx[kl * 256];
#pragma unroll
            for (int q = 0; q < 64; ++q) {
                float4 w4 = cw[q], x4 = cx[q];
                p = fmaf(x4.x, w4.x, p); p = fmaf(x4.y, w4.y, p);
                p = fmaf(x4.z, w4.z, p); p = fmaf(x4.w, w4.w, p);
            }
        }
        p += __shfl_xor(p, 1, 64); p += __shfl_xor(p, 2, 64);
        if (kl == 0 && c < 63) lgs[c] = p + charb[c];
        if (tid == 0) lgs[63] = -1e30f;
        __syncthreads();
        if (tid < 64) {
            float lg = (tid < 63) ? lgs[tid] : -1e30f;
            float mx = lg;
            for (int o = 32; o > 0; o >>= 1) mx = fmaxf(mx, __shfl_xor(mx, o, 64));
            float ex2 = (tid < 63) ? __expf(lg - mx) : 0.f;
            float sume = wsum64(ex2);
            if (tid < 63)
                preds[((size_t)prow * B_ + b) * CC + tid] = lg - mx - __logf(sume);
        }
    }
}

extern "C" void kernel_launch(void* const* d_in, const int* in_sizes, int n_in,
                              void* d_out, int out_size, void* d_ws, size_t ws_size,
                              hipStream_t stream) {
    const float* Lf   = (const float*)d_in[0];
    const float* gt   = (const float*)d_in[1];
    const float* phiw = (const float*)d_in[2];
    const float* phib = (const float*)d_in[3];
    const float* psiw = (const float*)d_in[4];
    const float* psib = (const float*)d_in[5];
    const float* wih0 = (const float*)d_in[6];
    const float* whh0 = (const float*)d_in[7];
    const float* bih0 = (const float*)d_in[8];
    const float* bhh0 = (const float*)d_in[9];
    const float* wih1 = (const float*)d_in[10];
    const float* whh1 = (const float*)d_in[11];
    const float* bih1 = (const float*)d_in[12];
    const float* bhh1 = (const float*)d_in[13];
    const float* charw = (const float*)d_in[14];
    const float* charb = (const float*)d_in[15];

    float* preds = (float*)d_out;
    float* atts  = (float*)d_out + (size_t)SS * B_ * CC;

    char* ws = (char*)d_ws;
    size_t off = 0;
    auto alloc = [&](size_t bytes) { size_t o = off; off = (off + bytes + 255) & ~(size_t)255; return o; };
    unsigned short* clT = (unsigned short*)(ws + alloc((size_t)B_ * M_ * T_ * 2));
    unsigned short* Lbf = (unsigned short*)(ws + alloc((size_t)B_ * T_ * D_ * 2));
    unsigned short* psibf = (unsigned short*)(ws + alloc((size_t)M_ * D_ * 2));
    float* gtT      = (float*)(ws + alloc((size_t)SS * CC * 64 * 4));
    float* h0p0     = (float*)(ws + alloc(H_ * B_ * 4));
    float* h0p1     = (float*)(ws + alloc(H_ * B_ * 4));
    float* h1p0     = (float*)(ws + alloc(H_ * B_ * 4));
    float* h1p1     = (float*)(ws + alloc(H_ * B_ * 4));
    float* hb0      = (float*)(ws + alloc(H_ * B_ * 4));
    float* hb1      = (float*)(ws + alloc(H_ * B_ * 4));
    float* c0       = (float*)(ws + alloc(H_ * B_ * 4));
    float* c1       = (float*)(ws + alloc(H_ * B_ * 4));
    float* ctxT0    = (float*)(ws + alloc(H_ * B_ * 4));
    float* ctxT1    = (float*)(ws + alloc(H_ * B_ * 4));
    float* ctxb0    = (float*)(ws + alloc(H_ * B_ * 4));
    float* ctxb1    = (float*)(ws + alloc(H_ * B_ * 4));
    float* cdb      = (float*)(ws + alloc(B_ * M_ * 4));
    float* energy_bt = (float*)(ws + alloc(B_ * T_ * 4));
    float* energyT   = (float*)(ws + alloc(B_ * T_ * 4));
    float* rS       = (float*)(ws + alloc(T_ * 4));
    float* dsS      = (float*)(ws + alloc(T_ * 4));
    int* badS       = (int*)(ws + alloc(T_ * 4));
    int* colZero    = (int*)(ws + alloc(T_ * 4));

    k_conv<<<2048, 256, 0, stream>>>(Lf, Lbf, (B_ * T_ * D_) / 4);
    k_conv<<<128, 256, 0, stream>>>(psiw, psibf, (M_ * D_) / 4);
    k_gemm_mfma<<<4096, 256, 0, stream>>>(Lbf, psibf, psib, clT);
    k_init<<<192, 256, 0, stream>>>(Lf, gt, gtT, h0p0, h1p0, c0, c1, ctxT0, ctxb0);

    float* h0p[2] = {h0p0, h0p1};
    float* h1p[2] = {h1p0, h1p1};
    float* hb[2]  = {hb0, hb1};
    float* ctxTb[2] = {ctxT0, ctxT1};
    float* ctxbb[2] = {ctxb0, ctxb1};
    for (int s = 0; s < SS; ++s) {
        int pi = s & 1, po = pi ^ 1;
        k_lstm0<<<128, 256, 0, stream>>>(s, gtT, ctxTb[pi], h0p[pi], h0p[po], c0,
                                         wih0, whh0, bih0, bhh0, colZero);
        k_lstm1<<<128, 256, 0, stream>>>(h0p[po], h1p[pi], h1p[po], c1, hb[pi],
                                         wih1, whh1, bih1, bhh1);
        k_phi<<<8, 256, 0, stream>>>(h1p[po], phiw, phib, cdb);
        k_energy<<<512, 128, 0, stream>>>(cdb, clT, energy_bt, energyT, colZero);
        k_cop<<<256, 256, 0, stream>>>(energyT, rS, dsS, badS);
        k_softctx<<<512, 256, 0, stream>>>(1, s, s - 1, energy_bt, colZero,
                                           rS, dsS, badS, Lbf,
                                           hb[po], ctxbb[pi], charw, charb,
                                           ctxTb[po], ctxbb[po], preds, atts);
    }
    // tail: charpred + preds for step 63 (h1b(63)=hb[1], ctx(63)=bufs[0])
    k_softctx<<<512, 256, 0, stream>>>(0, SS - 1, SS - 1, energy_bt, colZero,
                                       rS, dsS, badS, Lbf,
                                       hb[1], ctxbb[0], charw, charb,
                                       ctxTb[1], ctxbb[1], preds, atts);
}

// Round 14
// 8771.394 us; speedup vs baseline: 1.0551x; 1.0403x over previous
//
#include <hip/hip_runtime.h>
#include <hip/hip_bf16.h>
#include <math.h>

#define B_ 64
#define T_ 1024
#define D_ 512
#define H_ 512
#define M_ 256
#define CC 63
#define SS 64
#define INV_SQRT_2PI 0.3989422804014327f

typedef __attribute__((ext_vector_type(8))) short short8v;
typedef __attribute__((ext_vector_type(4))) float f32x4;

static __device__ __forceinline__ float bf2f(unsigned short u) {
    unsigned int x = ((unsigned int)u) << 16;
    return __uint_as_float(x);
}
static __device__ __forceinline__ unsigned short f2bf(float f) {
    unsigned int x = __float_as_uint(f);
    unsigned int r = (x + 0x7fff + ((x >> 16) & 1)) >> 16;
    return (unsigned short)r;
}
static __device__ __forceinline__ float sigm(float x) {
    return 1.f / (1.f + __expf(-x));
}
static __device__ __forceinline__ float wsum64(float v) {
    for (int o = 32; o > 0; o >>= 1) v += __shfl_xor(v, o, 64);
    return v;
}

// ---------------- prologue ----------------

__global__ __launch_bounds__(256) void k_conv(const float* __restrict__ src,
        unsigned short* __restrict__ dst, int n4) {
    int stride = gridDim.x * 256;
    for (int i = blockIdx.x * 256 + threadIdx.x; i < n4; i += stride) {
        float4 v = ((const float4*)src)[i];
        ushort4 o;
        o.x = f2bf(v.x); o.y = f2bf(v.y); o.z = f2bf(v.z); o.w = f2bf(v.w);
        ((ushort4*)dst)[i] = o;
    }
}

// MFMA bf16 GEMM (r2-proven): clT[b*256+m][t] = bf16(relu(Lbf x psibf^T + psib))
__global__ __launch_bounds__(256) void k_gemm_mfma(
        const unsigned short* __restrict__ Abf,
        const unsigned short* __restrict__ Bbf,
        const float* __restrict__ psib,
        unsigned short* __restrict__ clT) {
    __shared__ unsigned short As[64 * 40];
    __shared__ unsigned short Bs[64 * 40];
    __shared__ unsigned short Os[64 * 72];
    int tid = threadIdx.x;
    int p0 = (blockIdx.x >> 2) * 64;
    int m0 = (blockIdx.x & 3) * 64;
    int w = tid >> 6, l = tid & 63;
    int wp = (w & 1) * 32, wm = (w >> 1) * 32;
    f32x4 acc[2][2] = {};
    int srow = tid >> 2, sc = (tid & 3) * 8;
    for (int k0 = 0; k0 < 512; k0 += 32) {
        __syncthreads();
        *(short8v*)&As[srow * 40 + sc] = *(const short8v*)&Abf[(size_t)(p0 + srow) * 512 + k0 + sc];
        *(short8v*)&Bs[srow * 40 + sc] = *(const short8v*)&Bbf[(size_t)(m0 + srow) * 512 + k0 + sc];
        __syncthreads();
        int koff = (l >> 4) * 8;
        int rlo = l & 15;
        short8v a0 = *(short8v*)&As[(wp + rlo) * 40 + koff];
        short8v a1 = *(short8v*)&As[(wp + 16 + rlo) * 40 + koff];
        short8v b0 = *(short8v*)&Bs[(wm + rlo) * 40 + koff];
        short8v b1 = *(short8v*)&Bs[(wm + 16 + rlo) * 40 + koff];
        acc[0][0] = __builtin_amdgcn_mfma_f32_16x16x32_bf16(a0, b0, acc[0][0], 0, 0, 0);
        acc[0][1] = __builtin_amdgcn_mfma_f32_16x16x32_bf16(a0, b1, acc[0][1], 0, 0, 0);
        acc[1][0] = __builtin_amdgcn_mfma_f32_16x16x32_bf16(a1, b0, acc[1][0], 0, 0, 0);
        acc[1][1] = __builtin_amdgcn_mfma_f32_16x16x32_bf16(a1, b1, acc[1][1], 0, 0, 0);
    }
    __syncthreads();
#pragma unroll
    for (int pi = 0; pi < 2; ++pi)
#pragma unroll
        for (int mi = 0; mi < 2; ++mi)
#pragma unroll
            for (int r = 0; r < 4; ++r) {
                int tl = wp + pi * 16 + (l >> 4) * 4 + r;
                int ml = wm + mi * 16 + (l & 15);
                float v = fmaxf(acc[pi][mi][r] + psib[m0 + ml], 0.f);
                Os[ml * 72 + tl] = f2bf(v);
            }
    __syncthreads();
    int b = p0 >> 10, t0 = p0 & 1023;
    int mm = tid >> 2, c16 = (tid & 3) * 16;
    short8v v0 = *(short8v*)&Os[mm * 72 + c16];
    short8v v1 = *(short8v*)&Os[mm * 72 + c16 + 8];
    size_t base = ((size_t)(b * 256 + m0 + mm)) * 1024 + t0 + c16;
    *(short8v*)&clT[base] = v0;
    *(short8v*)&clT[base + 8] = v1;
}

__global__ __launch_bounds__(256) void k_init(const float* __restrict__ Lf,
        const float* __restrict__ gt,
        float* gtT, float* h0a, float* h1a, float* c0, float* c1,
        float* ctxT, float* ctxb) {
    int tid = threadIdx.x, blk = blockIdx.x;
    if (blk < 64) {
        for (int r = tid; r < CC * 64; r += 256) {
            int k = r >> 6, b = r & 63;
            gtT[blk * (CC * 64) + r] = gt[(b * SS + blk) * CC + k];
        }
    } else {
        int idx = (blk - 64) * 256 + tid;
        h0a[idx] = 0.f; h1a[idx] = 0.f; c0[idx] = 0.f; c1[idx] = 0.f;
        int d = idx >> 6, b = idx & 63;
        float v = Lf[(size_t)b * (T_ * D_) + d];
        ctxT[idx] = v;
        ctxb[b * 512 + d] = v;
    }
}

// ---------------- per-step kernels ----------------

// LSTM0 (blocks 0-127, r9-verbatim) + charpred(s-1) (blocks 128-191, r1 dual-role pattern)
__global__ __launch_bounds__(256) void k_lstm0(
        int s, const float* __restrict__ gtT, const float* __restrict__ ctxT,
        const float* __restrict__ h0in, float* __restrict__ h0out,
        float* __restrict__ c0,
        const float* __restrict__ wih0, const float* __restrict__ whh0,
        const float* __restrict__ bih0, const float* __restrict__ bhh0,
        int* __restrict__ colZero,
        const float* __restrict__ h1bp, const float* __restrict__ ctxb,
        const float* __restrict__ charw, const float* __restrict__ charb,
        float* __restrict__ preds) {
    __shared__ float xs[4096];
    __shared__ float wsm[16 * 68];
    __shared__ float ex[16 * 64];
    __shared__ float lgs[64];
    int tid = threadIdx.x, uid = blockIdx.x;
    if (uid >= 128) {
        // ---- charpred + preds for step s-1 (r11 k_soft branch, verbatim math) ----
        if (s > 0) {
            int b = uid - 128;
            float* cpx = xs;
            for (int i = tid; i < 1024; i += 256)
                cpx[i] = (i < 512) ? h1bp[b * 512 + i] : ctxb[b * 512 + (i - 512)];
            __syncthreads();
            int c = tid >> 2, kl = tid & 3;
            float p = 0.f;
            if (c < 63) {
                const float4* cw = (const float4*)&charw[(size_t)c * 1024 + kl * 256];
                const float4* cx = (const float4*)&cpx[kl * 256];
#pragma unroll
                for (int q = 0; q < 64; ++q) {
                    float4 w4 = cw[q], x4 = cx[q];
                    p = fmaf(x4.x, w4.x, p); p = fmaf(x4.y, w4.y, p);
                    p = fmaf(x4.z, w4.z, p); p = fmaf(x4.w, w4.w, p);
                }
            }
            p += __shfl_xor(p, 1, 64); p += __shfl_xor(p, 2, 64);
            if (kl == 0 && c < 63) lgs[c] = p + charb[c];
            if (tid == 0) lgs[63] = -1e30f;
            __syncthreads();
            if (tid < 64) {
                float lg = (tid < 63) ? lgs[tid] : -1e30f;
                float mx = lg;
                for (int o = 32; o > 0; o >>= 1) mx = fmaxf(mx, __shfl_xor(mx, o, 64));
                float ex2 = (tid < 63) ? __expf(lg - mx) : 0.f;
                float sume = wsum64(ex2);
                if (tid < 63)
                    preds[((size_t)(s - 1) * B_ + b) * CC + tid] = lg - mx - __logf(sume);
            }
        }
        return;
    }
    int r = tid >> 4, tb = tid & 15;
    float a0 = 0.f, a1 = 0.f, a2 = 0.f, a3 = 0.f;
    for (int kc = 0; kc < 17; ++kc) {
        int k0 = kc * 64;
        __syncthreads();
#pragma unroll
        for (int i = 0; i < 4; ++i) {
            int e4 = i * 256 + tid;
            int kk = e4 >> 4, b4 = (e4 & 15) * 4;
            int k = k0 + kk;
            float4 v;
            if (k < 63) {
                if (s > 0) v = *(const float4*)&gtT[(s - 1) * 4032 + k * 64 + b4];
                else { float o1 = (k == 0) ? 1.f : 0.f; v = make_float4(o1, o1, o1, o1); }
            } else if (k < 575)  v = *(const float4*)&ctxT[(k - 63) * 64 + b4];
            else if (k < 1087)   v = *(const float4*)&h0in[(k - 575) * 64 + b4];
            else                 v = make_float4(0.f, 0.f, 0.f, 0.f);
            *(float4*)&xs[kk * 64 + b4] = v;
        }
#pragma unroll
        for (int i = 0; i < 4; ++i) {
            int lidx = i * 256 + tid;
            int rr = lidx >> 6, kk = lidx & 63;
            int k = k0 + kk;
            int g2 = rr >> 2, uu = rr & 3;
            int jj = g2 * 512 + uid * 4 + uu;
            float wv;
            if (k < 575)       wv = wih0[(size_t)jj * 575 + k];
            else if (k < 1087) wv = whh0[(size_t)jj * 512 + (k - 575)];
            else               wv = 0.f;
            wsm[rr * 68 + kk] = wv;
        }
        __syncthreads();
        const float* wsr = &wsm[r * 68];
        const float* xsr = &xs[tb * 4];
#pragma unroll
        for (int kk = 0; kk < 64; ++kk) {
            float wv = wsr[kk];
            float4 x4 = *(const float4*)&xsr[kk * 64];
            a0 = fmaf(wv, x4.x, a0);
            a1 = fmaf(wv, x4.y, a1);
            a2 = fmaf(wv, x4.z, a2);
            a3 = fmaf(wv, x4.w, a3);
        }
    }
    {
        int g2 = r >> 2, uu = r & 3;
        int j = g2 * 512 + uid * 4 + uu;
        float bias = bih0[j] + bhh0[j];
        __syncthreads();
        *(float4*)&ex[r * 64 + tb * 4] =
            make_float4(a0 + bias, a1 + bias, a2 + bias, a3 + bias);
    }
    __syncthreads();
    {
        int ui = tid >> 6, b = tid & 63;
        float gi = ex[(0 * 4 + ui) * 64 + b];
        float gf = ex[(1 * 4 + ui) * 64 + b];
        float gg = ex[(2 * 4 + ui) * 64 + b];
        float go = ex[(3 * 4 + ui) * 64 + b];
        int u = uid * 4 + ui;
        float cv = c0[u * 64 + b];
        float cn = sigm(gf) * cv + sigm(gi) * tanhf(gg);
        float hn = sigm(go) * tanhf(cn);
        c0[u * 64 + b] = cn;
        h0out[u * 64 + b] = hn;
    }
    if (uid == 0) {
        for (int i = tid; i < 1024; i += 256) colZero[i] = 1;
    }
}

// LSTM1: 128 blocks x 4 units (r9-proven, verbatim)
__global__ __launch_bounds__(256) void k_lstm1(
        const float* __restrict__ h0cur, const float* __restrict__ h1in,
        float* __restrict__ h1out, float* __restrict__ c1,
        float* __restrict__ h1bout,
        const float* __restrict__ wih1, const float* __restrict__ whh1,
        const float* __restrict__ bih1, const float* __restrict__ bhh1) {
    __shared__ float xs[4096];
    __shared__ float wsm[16 * 68];
    __shared__ float ex[16 * 64];
    int tid = threadIdx.x, uid = blockIdx.x;
    int r = tid >> 4, tb = tid & 15;
    float a0 = 0.f, a1 = 0.f, a2 = 0.f, a3 = 0.f;
    for (int kc = 0; kc < 16; ++kc) {
        int k0 = kc * 64;
        __syncthreads();
#pragma unroll
        for (int i = 0; i < 4; ++i) {
            int e4 = i * 256 + tid;
            int kk = e4 >> 4, b4 = (e4 & 15) * 4;
            int k = k0 + kk;
            float4 v = (k < 512) ? *(const float4*)&h0cur[k * 64 + b4]
                                 : *(const float4*)&h1in[(k - 512) * 64 + b4];
            *(float4*)&xs[kk * 64 + b4] = v;
        }
#pragma unroll
        for (int i = 0; i < 4; ++i) {
            int lidx = i * 256 + tid;
            int rr = lidx >> 6, kk = lidx & 63;
            int k = k0 + kk;
            int g2 = rr >> 2, uu = rr & 3;
            int jj = g2 * 512 + uid * 4 + uu;
            float wv = (k < 512) ? wih1[(size_t)jj * 512 + k]
                                 : whh1[(size_t)jj * 512 + (k - 512)];
            wsm[rr * 68 + kk] = wv;
        }
        __syncthreads();
        const float* wsr = &wsm[r * 68];
        const float* xsr = &xs[tb * 4];
#pragma unroll
        for (int kk = 0; kk < 64; ++kk) {
            float wv = wsr[kk];
            float4 x4 = *(const float4*)&xsr[kk * 64];
            a0 = fmaf(wv, x4.x, a0);
            a1 = fmaf(wv, x4.y, a1);
            a2 = fmaf(wv, x4.z, a2);
            a3 = fmaf(wv, x4.w, a3);
        }
    }
    {
        int g2 = r >> 2, uu = r & 3;
        int j = g2 * 512 + uid * 4 + uu;
        float bias = bih1[j] + bhh1[j];
        __syncthreads();
        *(float4*)&ex[r * 64 + tb * 4] =
            make_float4(a0 + bias, a1 + bias, a2 + bias, a3 + bias);
    }
    __syncthreads();
    {
        int ui = tid >> 6, b = tid & 63;
        float gi = ex[(0 * 4 + ui) * 64 + b];
        float gf = ex[(1 * 4 + ui) * 64 + b];
        float gg = ex[(2 * 4 + ui) * 64 + b];
        float go = ex[(3 * 4 + ui) * 64 + b];
        int u = uid * 4 + ui;
        float cv = c1[u * 64 + b];
        float cn = sigm(gf) * cv + sigm(gi) * tanhf(gg);
        float hn = sigm(go) * tanhf(cn);
        c1[u * 64 + b] = cn;
        h1out[u * 64 + b] = hn;
        h1bout[b * 512 + u] = hn;
    }
}

// phi once (r11-proven, verbatim)
__global__ __launch_bounds__(256) void k_phi(
        const float* __restrict__ h1u,
        const float* __restrict__ phiw, const float* __restrict__ phib,
        float* __restrict__ cdb) {
    __shared__ float xs[4096];
    __shared__ float wsm[32 * 68];
    int tid = threadIdx.x;
    int m0 = blockIdx.x * 32;
    int mr = tid >> 3, bq = tid & 7;
    float bias = phib[m0 + mr];
    float acc[8] = {bias, bias, bias, bias, bias, bias, bias, bias};
    for (int kc = 0; kc < 8; ++kc) {
        int k0 = kc * 64;
        __syncthreads();
#pragma unroll
        for (int i = 0; i < 4; ++i) {
            int idx4 = i * 256 + tid;
            int kk = idx4 >> 4, b4 = (idx4 & 15) * 4;
            *(float4*)&xs[kk * 64 + b4] = *(const float4*)&h1u[(k0 + kk) * 64 + b4];
        }
#pragma unroll
        for (int i = 0; i < 2; ++i) {
            int idx4 = i * 256 + tid;
            int mm = idx4 >> 4, kk4 = (idx4 & 15) * 4;
            *(float4*)&wsm[mm * 68 + kk4] = *(const float4*)&phiw[(size_t)(m0 + mm) * 512 + k0 + kk4];
        }
        __syncthreads();
        const float* wr = &wsm[mr * 68];
#pragma unroll
        for (int kk = 0; kk < 64; ++kk) {
            float wv = wr[kk];
            const float* xp = &xs[kk * 64 + bq * 8];
#pragma unroll
            for (int j = 0; j < 8; ++j)
                acc[j] = fmaf(xp[j], wv, acc[j]);
        }
    }
#pragma unroll
    for (int j = 0; j < 8; ++j)
        cdb[(bq * 8 + j) * 256 + m0 + mr] = fmaxf(acc[j], 0.f);
}

// energy: bit-exact per-t serial-m chains, vectorized ushort8 loads.
// 128 blocks = b x 2 halves; 64 threads; thread owns 8 consecutive t.
__global__ __launch_bounds__(64) void k_energy(
        const float* __restrict__ cdb,
        const unsigned short* __restrict__ clT,
        float* __restrict__ energy_bt, float* __restrict__ energyT,
        int* __restrict__ colZero) {
    __shared__ float cdl[256];
    int tid = threadIdx.x;
    int b = blockIdx.x >> 1, half = blockIdx.x & 1;
#pragma unroll
    for (int j = 0; j < 4; ++j)
        cdl[j * 64 + tid] = cdb[b * 256 + j * 64 + tid];
    __syncthreads();
    int t8 = half * 512 + tid * 8;
    float e[8] = {0.f, 0.f, 0.f, 0.f, 0.f, 0.f, 0.f, 0.f};
    const unsigned short* base = clT + ((size_t)(b * 256)) * 1024 + t8;
#pragma unroll 8
    for (int m = 0; m < 256; ++m) {
        short8v v = *(const short8v*)(base + (size_t)m * 1024);
        float c = cdl[m];
        e[0] = fmaf(c, bf2f((unsigned short)v[0]), e[0]);
        e[1] = fmaf(c, bf2f((unsigned short)v[1]), e[1]);
        e[2] = fmaf(c, bf2f((unsigned short)v[2]), e[2]);
        e[3] = fmaf(c, bf2f((unsigned short)v[3]), e[3]);
        e[4] = fmaf(c, bf2f((unsigned short)v[4]), e[4]);
        e[5] = fmaf(c, bf2f((unsigned short)v[5]), e[5]);
        e[6] = fmaf(c, bf2f((unsigned short)v[6]), e[6]);
        e[7] = fmaf(c, bf2f((unsigned short)v[7]), e[7]);
    }
#pragma unroll
    for (int j = 0; j < 8; ++j) {
        int t = t8 + j;
        energyT[t * 64 + b] = e[j];
        if (e[j] != 0.f) colZero[t] = 0;
    }
    *(float4*)&energy_bt[b * 1024 + t8] = make_float4(e[0], e[1], e[2], e[3]);
    *(float4*)&energy_bt[b * 1024 + t8 + 4] = make_float4(e[4], e[5], e[6], e[7]);
}

// copula column stats (r9-proven, verbatim): 256 blocks x 4 t
__global__ __launch_bounds__(256) void k_cop(
        const float* __restrict__ energyT,
        float* __restrict__ rS, float* __restrict__ dsS, int* __restrict__ badS) {
    int tid = threadIdx.x;
    int wv = tid >> 6, b = tid & 63;
    int t = blockIdx.x * 4 + wv;
    if (t >= 1 && t < 1023) {
        float e = energyT[t * 64 + b];
        float a = energyT[(t - 1) * 64 + b];
        float ma = wsum64(a) * (1.f / 64.f);
        float mb = wsum64(e) * (1.f / 64.f);
        float am = a - ma, bm = e - mb;
        float sab = wsum64(am * bm);
        float saa = wsum64(am * am);
        float sbb = wsum64(bm * bm);
        int aeq = __all(a == e);
        float r = sab / sqrtf(saa * sbb + 1e-12f);
        float det = 1.f - r * r;
        int bad = (det < 0.01f || aeq) ? 1 : 0;
        float ds = fmaxf(det, 1e-6f);
        if (b == 0) { rS[t] = r; dsS[t] = ds; badS[t] = bad; }
    }
}

// vals + softmax + atts (+ charpred/preds for prow; tail only): 64 blocks (r11-verbatim)
__global__ __launch_bounds__(256) void k_soft(
        int doSM, int s, int prow,
        const float* __restrict__ energy_bt, const int* __restrict__ colZero,
        const float* __restrict__ rS, const float* __restrict__ dsS,
        const int* __restrict__ badS,
        const float* __restrict__ h1bp, const float* __restrict__ ctxb,
        const float* __restrict__ charw, const float* __restrict__ charb,
        float* __restrict__ preds, float* __restrict__ atts,
        float* __restrict__ attbuf) {
    __shared__ float e_l[1024];
    __shared__ float red[256];
    __shared__ int zred[256];
    __shared__ float cpx[1024];
    __shared__ float lgs[64];
    int tid = threadIdx.x, b = blockIdx.x;
    if (doSM) {
        *(float4*)&e_l[tid * 4] = *(const float4*)&energy_bt[b * 1024 + tid * 4];
        int z = colZero[tid] | colZero[256 + tid] | colZero[512 + tid] | colZero[768 + tid];
        zred[tid] = z;
        __syncthreads();
        for (int o = 128; o > 0; o >>= 1) {
            if (tid < o) zred[tid] |= zred[tid + o];
            __syncthreads();
        }
        int zf = zred[0];
        float4 rv = *(const float4*)&rS[tid * 4];
        float4 dv = *(const float4*)&dsS[tid * 4];
        int4 bv = *(const int4*)&badS[tid * 4];
        float rvv[4] = {rv.x, rv.y, rv.z, rv.w};
        float dvv[4] = {dv.x, dv.y, dv.z, dv.w};
        int bvv[4] = {bv.x, bv.y, bv.z, bv.w};
        float vals[4];
#pragma unroll
        for (int i = 0; i < 4; ++i) {
            int t = tid * 4 + i;
            float e = e_l[t];
            if (zf) {
                vals[i] = e;
            } else {
                float cp;
                if (t == 0 || t == 1023) cp = 1.f;
                else if (bvv[i]) cp = 10.f;
                else {
                    float a = e_l[t - 1];
                    float r = rvv[i], ds = dvv[i];
                    float quad = r * r * (a * a + e * e) - 2.f * r * a * e;
                    cp = __expf(-0.5f * quad / ds) / sqrtf(ds);
                }
                vals[i] = __expf(-0.5f * e * e) * INV_SQRT_2PI * cp;
            }
        }
        float lm = fmaxf(fmaxf(vals[0], vals[1]), fmaxf(vals[2], vals[3]));
        red[tid] = lm;
        __syncthreads();
        for (int o = 128; o > 0; o >>= 1) {
            if (tid < o) red[tid] = fmaxf(red[tid], red[tid + o]);
            __syncthreads();
        }
        float M = red[0];
        __syncthreads();
        float e0 = __expf(vals[0] - M), e1 = __expf(vals[1] - M);
        float e2 = __expf(vals[2] - M), e3 = __expf(vals[3] - M);
        red[tid] = e0 + e1 + e2 + e3;
        __syncthreads();
        for (int o = 128; o > 0; o >>= 1) {
            if (tid < o) red[tid] += red[tid + o];
            __syncthreads();
        }
        float inv = 1.f / red[0];
        float4 a4 = make_float4(e0 * inv, e1 * inv, e2 * inv, e3 * inv);
        *(float4*)&attbuf[b * 1024 + tid * 4] = a4;
        *(float4*)&atts[((size_t)s * B_ + b) * 1024 + tid * 4] = a4;
    }
    if (prow >= 0) {
        __syncthreads();
        for (int i = tid; i < 1024; i += 256)
            cpx[i] = (i < 512) ? h1bp[b * 512 + i] : ctxb[b * 512 + (i - 512)];
        __syncthreads();
        int c = tid >> 2, kl = tid & 3;
        float p = 0.f;
        if (c < 63) {
            const float4* cw = (const float4*)&charw[(size_t)c * 1024 + kl * 256];
            const float4* cx = (const float4*)&cpx[kl * 256];
#pragma unroll
            for (int q = 0; q < 64; ++q) {
                float4 w4 = cw[q], x4 = cx[q];
                p = fmaf(x4.x, w4.x, p); p = fmaf(x4.y, w4.y, p);
                p = fmaf(x4.z, w4.z, p); p = fmaf(x4.w, w4.w, p);
            }
        }
        p += __shfl_xor(p, 1, 64); p += __shfl_xor(p, 2, 64);
        if (kl == 0 && c < 63) lgs[c] = p + charb[c];
        if (tid == 0) lgs[63] = -1e30f;
        __syncthreads();
        if (tid < 64) {
            float lg = (tid < 63) ? lgs[tid] : -1e30f;
            float mx = lg;
            for (int o = 32; o > 0; o >>= 1) mx = fmaxf(mx, __shfl_xor(mx, o, 64));
            float ex2 = (tid < 63) ? __expf(lg - mx) : 0.f;
            float sume = wsum64(ex2);
            if (tid < 63)
                preds[((size_t)prow * B_ + b) * CC + tid] = lg - mx - __logf(sume);
        }
    }
}

// context: 512 blocks = b x 8 d-stripes of 64 (r9-proven, verbatim)
__global__ __launch_bounds__(256) void k_ctx(
        const float* __restrict__ attbuf, const unsigned short* __restrict__ Lbf,
        float* __restrict__ ctxT, float* __restrict__ ctxb) {
    __shared__ float att[1056];
    __shared__ float red2[256];
    int tid = threadIdx.x;
    int b = blockIdx.x >> 3, dq = blockIdx.x & 7, d0 = dq * 64;
    {
        float4 a4 = *(const float4*)&attbuf[b * 1024 + tid * 4];
        int t = tid * 4;
        int pk = t + (t >> 5);
        att[pk] = a4.x; att[pk + 1] = a4.y; att[pk + 2] = a4.z; att[pk + 3] = a4.w;
    }
    __syncthreads();
    int tc = tid >> 3, dg = tid & 7;
    const unsigned short* Lb = Lbf + (size_t)b * 524288 + (size_t)tc * 32 * 512 + d0 + dg * 8;
    float acc[8] = {0.f, 0.f, 0.f, 0.f, 0.f, 0.f, 0.f, 0.f};
#pragma unroll
    for (int i = 0; i < 32; ++i) {
        float wv = att[tc * 33 + i];
        short8v v = *(const short8v*)(Lb + (size_t)i * 512);
        acc[0] = fmaf(wv, bf2f((unsigned short)v[0]), acc[0]);
        acc[1] = fmaf(wv, bf2f((unsigned short)v[1]), acc[1]);
        acc[2] = fmaf(wv, bf2f((unsigned short)v[2]), acc[2]);
        acc[3] = fmaf(wv, bf2f((unsigned short)v[3]), acc[3]);
        acc[4] = fmaf(wv, bf2f((unsigned short)v[4]), acc[4]);
        acc[5] = fmaf(wv, bf2f((unsigned short)v[5]), acc[5]);
        acc[6] = fmaf(wv, bf2f((unsigned short)v[6]), acc[6]);
        acc[7] = fmaf(wv, bf2f((unsigned short)v[7]), acc[7]);
    }
#pragma unroll
    for (int j = 0; j < 8; ++j) {
        acc[j] += __shfl_xor(acc[j], 8, 64);
        acc[j] += __shfl_xor(acc[j], 16, 64);
        acc[j] += __shfl_xor(acc[j], 32, 64);
    }
    int w = tid >> 6;
    if ((tid & 56) == 0) {
#pragma unroll
        for (int j = 0; j < 8; ++j) red2[w * 64 + dg * 8 + j] = acc[j];
    }
    __syncthreads();
    if (tid < 64) {
        float cv = red2[tid] + red2[64 + tid] + red2[128 + tid] + red2[192 + tid];
        ctxT[(d0 + tid) * 64 + b] = cv;
        ctxb[b * 512 + d0 + tid] = cv;
    }
}

extern "C" void kernel_launch(void* const* d_in, const int* in_sizes, int n_in,
                              void* d_out, int out_size, void* d_ws, size_t ws_size,
                              hipStream_t stream) {
    const float* Lf   = (const float*)d_in[0];
    const float* gt   = (const float*)d_in[1];
    const float* phiw = (const float*)d_in[2];
    const float* phib = (const float*)d_in[3];
    const float* psiw = (const float*)d_in[4];
    const float* psib = (const float*)d_in[5];
    const float* wih0 = (const float*)d_in[6];
    const float* whh0 = (const float*)d_in[7];
    const float* bih0 = (const float*)d_in[8];
    const float* bhh0 = (const float*)d_in[9];
    const float* wih1 = (const float*)d_in[10];
    const float* whh1 = (const float*)d_in[11];
    const float* bih1 = (const float*)d_in[12];
    const float* bhh1 = (const float*)d_in[13];
    const float* charw = (const float*)d_in[14];
    const float* charb = (const float*)d_in[15];

    float* preds = (float*)d_out;
    float* atts  = (float*)d_out + (size_t)SS * B_ * CC;

    char* ws = (char*)d_ws;
    size_t off = 0;
    auto alloc = [&](size_t bytes) { size_t o = off; off = (off + bytes + 255) & ~(size_t)255; return o; };
    unsigned short* clT = (unsigned short*)(ws + alloc((size_t)B_ * M_ * T_ * 2));
    unsigned short* Lbf = (unsigned short*)(ws + alloc((size_t)B_ * T_ * D_ * 2));
    unsigned short* psibf = (unsigned short*)(ws + alloc((size_t)M_ * D_ * 2));
    float* gtT      = (float*)(ws + alloc((size_t)SS * CC * 64 * 4));
    float* h0p0     = (float*)(ws + alloc(H_ * B_ * 4));
    float* h0p1     = (float*)(ws + alloc(H_ * B_ * 4));
    float* h1p0     = (float*)(ws + alloc(H_ * B_ * 4));
    float* h1p1     = (float*)(ws + alloc(H_ * B_ * 4));
    float* hb0      = (float*)(ws + alloc(H_ * B_ * 4));
    float* hb1      = (float*)(ws + alloc(H_ * B_ * 4));
    float* c0       = (float*)(ws + alloc(H_ * B_ * 4));
    float* c1       = (float*)(ws + alloc(H_ * B_ * 4));
    float* ctxT     = (float*)(ws + alloc(H_ * B_ * 4));
    float* ctxb     = (float*)(ws + alloc(H_ * B_ * 4));
    float* cdb      = (float*)(ws + alloc(B_ * M_ * 4));
    float* energy_bt = (float*)(ws + alloc(B_ * T_ * 4));
    float* energyT   = (float*)(ws + alloc(B_ * T_ * 4));
    float* rS       = (float*)(ws + alloc(T_ * 4));
    float* dsS      = (float*)(ws + alloc(T_ * 4));
    int* badS       = (int*)(ws + alloc(T_ * 4));
    int* colZero    = (int*)(ws + alloc(T_ * 4));
    float* attbuf   = (float*)(ws + alloc(B_ * T_ * 4));

    k_conv<<<2048, 256, 0, stream>>>(Lf, Lbf, (B_ * T_ * D_) / 4);
    k_conv<<<128, 256, 0, stream>>>(psiw, psibf, (M_ * D_) / 4);
    k_gemm_mfma<<<4096, 256, 0, stream>>>(Lbf, psibf, psib, clT);
    k_init<<<192, 256, 0, stream>>>(Lf, gt, gtT, h0p0, h1p0, c0, c1, ctxT, ctxb);

    float* h0p[2] = {h0p0, h0p1};
    float* h1p[2] = {h1p0, h1p1};
    float* hb[2]  = {hb0, hb1};
    for (int s = 0; s < SS; ++s) {
        int pi = s & 1, po = pi ^ 1;
        k_lstm0<<<192, 256, 0, stream>>>(s, gtT, ctxT, h0p[pi], h0p[po], c0,
                                         wih0, whh0, bih0, bhh0, colZero,
                                         hb[po], ctxb, charw, charb, preds);
        k_lstm1<<<128, 256, 0, stream>>>(h0p[po], h1p[pi], h1p[po], c1, hb[pi],
                                         wih1, whh1, bih1, bhh1);
        k_phi<<<8, 256, 0, stream>>>(h1p[po], phiw, phib, cdb);
        k_energy<<<128, 64, 0, stream>>>(cdb, clT, energy_bt, energyT, colZero);
        k_cop<<<256, 256, 0, stream>>>(energyT, rS, dsS, badS);
        k_soft<<<64, 256, 0, stream>>>(1, s, -1, energy_bt, colZero, rS, dsS, badS,
                                       hb[po], ctxb, charw, charb,
                                       preds, atts, attbuf);
        k_ctx<<<512, 256, 0, stream>>>(attbuf, Lbf, ctxT, ctxb);
    }
    // tail: charpred + preds for step 63 (h1b of step 63 = hb[1])
    k_soft<<<64, 256, 0, stream>>>(0, SS - 1, SS - 1, energy_bt, colZero, rS, dsS, badS,
                                   hb[1], ctxb, charw, charb, preds, atts, attbuf);
}